// Round 2
// baseline (35.387 us; speedup 1.0000x reference)
//
#include <hip/hip_runtime.h>

// Advection: out[b,i,j] = (s[b,min(i+1,H-1),j]-s[b,i,j])*v[b,i,j,0]
//                       + (s[b,i,min(j+1,W-1)]-s[b,i,j])*v[b,i,j,1]
// B=32, H=W=512, fp32. Memory-bound elementwise stencil.
// 8 px/thread; nontemporal on the no-reuse streams (velocity, output).

#define H 512
#define W 512
#define PLANE (H * W)   // 262144

typedef float f4 __attribute__((ext_vector_type(4)));

__global__ __launch_bounds__(256) void advect_kernel(
    const float* __restrict__ s,
    const float* __restrict__ v,
    float* __restrict__ out)
{
    const int t = blockIdx.x * blockDim.x + threadIdx.x;
    const int q = t << 3;                 // flat pixel index (8 px/thread)
    const int b   = q >> 18;              // / PLANE
    const int rem = q & (PLANE - 1);
    const int i   = rem >> 9;             // / W
    const int j   = rem & (W - 1);

    const float* srow   = s + (size_t)b * PLANE + (size_t)i * W;
    const int    idn    = (i + 1 < H) ? (i + 1) : (H - 1);
    const float* srowdn = s + (size_t)b * PLANE + (size_t)idn * W;

    // state: cached loads (row i+1 has cross-block reuse)
    const f4 s0a = *reinterpret_cast<const f4*>(srow + j);
    const f4 s0b = *reinterpret_cast<const f4*>(srow + j + 4);
    const f4 sda = *reinterpret_cast<const f4*>(srowdn + j);
    const f4 sdb = *reinterpret_cast<const f4*>(srowdn + j + 4);
    // right neighbor of px j+7 is j+8, clamped to W-1 (== s0b.w at row edge)
    const float s8 = (j + 8 < W) ? srow[j + 8] : s0b.w;

    // velocity: streaming loads (no reuse)
    const f4* vp = reinterpret_cast<const f4*>(v + (size_t)q * 2);
    const f4 v0 = __builtin_nontemporal_load(vp + 0);
    const f4 v1 = __builtin_nontemporal_load(vp + 1);
    const f4 v2 = __builtin_nontemporal_load(vp + 2);
    const f4 v3 = __builtin_nontemporal_load(vp + 3);

    f4 o0, o1;
    o0.x = (sda.x - s0a.x) * v0.x + (s0a.y - s0a.x) * v0.y;
    o0.y = (sda.y - s0a.y) * v0.z + (s0a.z - s0a.y) * v0.w;
    o0.z = (sda.z - s0a.z) * v1.x + (s0a.w - s0a.z) * v1.y;
    o0.w = (sda.w - s0a.w) * v1.z + (s0b.x - s0a.w) * v1.w;
    o1.x = (sdb.x - s0b.x) * v2.x + (s0b.y - s0b.x) * v2.y;
    o1.y = (sdb.y - s0b.y) * v2.z + (s0b.z - s0b.y) * v2.w;
    o1.z = (sdb.z - s0b.z) * v3.x + (s0b.w - s0b.z) * v3.y;
    o1.w = (sdb.w - s0b.w) * v3.z + (s8    - s0b.w) * v3.w;

    f4* op = reinterpret_cast<f4*>(out + q);
    __builtin_nontemporal_store(o0, op + 0);
    __builtin_nontemporal_store(o1, op + 1);
}

extern "C" void kernel_launch(void* const* d_in, const int* in_sizes, int n_in,
                              void* d_out, int out_size, void* d_ws, size_t ws_size,
                              hipStream_t stream) {
    const float* s = (const float*)d_in[0];   // [32,512,512,1] f32
    const float* v = (const float*)d_in[1];   // [32,512,512,2] f32
    float* out = (float*)d_out;               // [32,512,512,1] f32

    const int n_pixels = 32 * PLANE;          // 8,388,608
    const int threads = n_pixels / 8;         // 1,048,576
    const int block = 256;
    const int grid = threads / block;         // 4096
    advect_kernel<<<grid, block, 0, stream>>>(s, v, out);
}

// Round 3
// 26.769 us; speedup vs baseline: 1.3220x; 1.3220x over previous
//
#include <hip/hip_runtime.h>

// Advection: out[b,i,j] = (s[b,min(i+1,H-1),j]-s[b,i,j])*v[b,i,j,0]
//                       + (s[b,i,min(j+1,W-1)]-s[b,i,j])*v[b,i,j,1]
// B=32, H=W=512, fp32. Memory-bound elementwise stencil.
// Round-1 structure (4 px/thread, perfectly coalesced 16B/lane) +
// nontemporal STORE only (output has zero reuse; don't pollute L2).

#define H 512
#define W 512
#define PLANE (H * W)   // 262144

typedef float f4 __attribute__((ext_vector_type(4)));

__global__ __launch_bounds__(256) void advect_kernel(
    const float* __restrict__ s,
    const float* __restrict__ v,
    float* __restrict__ out)
{
    const int t = blockIdx.x * blockDim.x + threadIdx.x;
    const int q = t << 2;                 // flat pixel index (4 pixels/thread)
    const int b   = q >> 18;              // / PLANE
    const int rem = q & (PLANE - 1);
    const int i   = rem >> 9;             // / W
    const int j   = rem & (W - 1);

    const float* srow   = s + (size_t)b * PLANE + (size_t)i * W;
    const int    idn    = (i + 1 < H) ? (i + 1) : (H - 1);
    const float* srowdn = s + (size_t)b * PLANE + (size_t)idn * W;

    const f4 s0 = *reinterpret_cast<const f4*>(srow + j);
    const f4 sd = *reinterpret_cast<const f4*>(srowdn + j);
    // right neighbor of pixel j+3 is j+4, clamped to W-1 (== s0.w at row edge)
    const float s4 = (j + 4 < W) ? srow[j + 4] : s0.w;

    const f4 v01 = *reinterpret_cast<const f4*>(v + (size_t)q * 2);
    const f4 v23 = *reinterpret_cast<const f4*>(v + (size_t)q * 2 + 4);

    f4 o;
    o.x = (sd.x - s0.x) * v01.x + (s0.y - s0.x) * v01.y;
    o.y = (sd.y - s0.y) * v01.z + (s0.z - s0.y) * v01.w;
    o.z = (sd.z - s0.z) * v23.x + (s0.w - s0.z) * v23.y;
    o.w = (sd.w - s0.w) * v23.z + (s4   - s0.w) * v23.w;

    __builtin_nontemporal_store(o, reinterpret_cast<f4*>(out + q));
}

extern "C" void kernel_launch(void* const* d_in, const int* in_sizes, int n_in,
                              void* d_out, int out_size, void* d_ws, size_t ws_size,
                              hipStream_t stream) {
    const float* s = (const float*)d_in[0];   // [32,512,512,1] f32
    const float* v = (const float*)d_in[1];   // [32,512,512,2] f32
    float* out = (float*)d_out;               // [32,512,512,1] f32

    const int n_pixels = 32 * PLANE;          // 8,388,608
    const int threads = n_pixels / 4;         // 2,097,152
    const int block = 256;
    const int grid = threads / block;         // 8192
    advect_kernel<<<grid, block, 0, stream>>>(s, v, out);
}